// Round 1
// baseline (226.526 us; speedup 1.0000x reference)
//
#include <hip/hip_runtime.h>

// Problem constants (from reference): B=64, I=512, H=1024, D=I+H=1536
constexpr int Bn = 64;
constexpr int In = 512;
constexpr int Hn = 1024;
constexpr int Dn = 1536;
constexpr float ALPHA = 0.001f;

// One wave (64 lanes) per output row (b,k).
//   Phase 1: load wih[b,k,:] (24 floats/lane as 6x float4) + x[b,:] chunks,
//            wave-reduce the dot product, y = tanh(dot + bih[k]).
//   Phase 2: wih_new[b,k,:] = wih + ALPHA*(y*x*Wa + x*Wb + y*Wc + Wd)
//            using the register-resident wih/x values (wih read ONCE from HBM).
// Row mapping row = k*64 + b: the 4 waves of a block share k -> Wih_a..d rows
// are L1-resident; x[b] (393 KB total) is L2-resident.
__global__ __launch_bounds__(256) void prnn_fused_kernel(
    const float* __restrict__ inputs,   // B x I
    const float* __restrict__ hidden,   // B x H
    const float* __restrict__ wih,      // B x H x D
    const float* __restrict__ Wa,       // H x D
    const float* __restrict__ Wb,       // H x D
    const float* __restrict__ Wc,       // H x D
    const float* __restrict__ Wd,       // H x D
    const float* __restrict__ bih,      // H
    float* __restrict__ out_hidden,     // B x H
    float* __restrict__ out_wih)        // B x H x D
{
    const int wave = threadIdx.x >> 6;
    const int lane = threadIdx.x & 63;
    const int row  = (blockIdx.x << 2) + wave;  // row = k*64 + b
    const int k = row >> 6;
    const int b = row & 63;

    const size_t woff = ((size_t)b * Hn + k) * Dn;
    const float* __restrict__ wrow = wih + woff;

    float4 w4[6];
    float4 x4[6];
    float acc = 0.0f;

    #pragma unroll
    for (int c = 0; c < 6; ++c) {
        const int idx = c * 256 + lane * 4;     // 0..1535, float4-aligned
        w4[c] = *(const float4*)(wrow + idx);
        // chunks 0-1 cover x[0..511] = inputs[b,:], chunks 2-5 cover hidden[b,:]
        const float4 xv = (c < 2)
            ? *(const float4*)(inputs + b * In + idx)
            : *(const float4*)(hidden + b * Hn + (idx - In));
        x4[c] = xv;
        acc += w4[c].x * xv.x + w4[c].y * xv.y
             + w4[c].z * xv.z + w4[c].w * xv.w;
    }

    // 64-lane butterfly reduction: all lanes end up with the full dot product
    #pragma unroll
    for (int off = 32; off > 0; off >>= 1)
        acc += __shfl_xor(acc, off, 64);

    const float y = tanhf(acc + bih[k]);
    if (lane == 0) out_hidden[b * Hn + k] = y;

    const float* __restrict__ wa = Wa + k * Dn;
    const float* __restrict__ wb = Wb + k * Dn;
    const float* __restrict__ wc = Wc + k * Dn;
    const float* __restrict__ wd = Wd + k * Dn;
    float* __restrict__ orow = out_wih + woff;

    #pragma unroll
    for (int c = 0; c < 6; ++c) {
        const int idx = c * 256 + lane * 4;
        const float4 a4 = *(const float4*)(wa + idx);
        const float4 b4 = *(const float4*)(wb + idx);
        const float4 c4 = *(const float4*)(wc + idx);
        const float4 d4 = *(const float4*)(wd + idx);
        float4 o;
        o.x = w4[c].x + ALPHA * (y * x4[c].x * a4.x + x4[c].x * b4.x + y * c4.x + d4.x);
        o.y = w4[c].y + ALPHA * (y * x4[c].y * a4.y + x4[c].y * b4.y + y * c4.y + d4.y);
        o.z = w4[c].z + ALPHA * (y * x4[c].z * a4.z + x4[c].z * b4.z + y * c4.z + d4.z);
        o.w = w4[c].w + ALPHA * (y * x4[c].w * a4.w + x4[c].w * b4.w + y * c4.w + d4.w);
        *(float4*)(orow + idx) = o;
    }
}

extern "C" void kernel_launch(void* const* d_in, const int* in_sizes, int n_in,
                              void* d_out, int out_size, void* d_ws, size_t ws_size,
                              hipStream_t stream) {
    const float* inputs = (const float*)d_in[0];
    const float* hidden = (const float*)d_in[1];
    const float* wih    = (const float*)d_in[2];
    const float* Wa     = (const float*)d_in[3];
    const float* Wb     = (const float*)d_in[4];
    const float* Wc     = (const float*)d_in[5];
    const float* Wd     = (const float*)d_in[6];
    const float* bih    = (const float*)d_in[7];
    // d_in[8] = W_dop, d_in[9] = b_dop: only feed _dopamine, which is not
    // returned by the reference -> dead code, skipped.

    float* out_hidden = (float*)d_out;                  // B*H floats
    float* out_wih    = (float*)d_out + (size_t)Bn * Hn; // B*H*D floats

    const int rows = Bn * Hn;          // 65536 rows, 4 rows (waves) per block
    prnn_fused_kernel<<<dim3(rows / 4), dim3(256), 0, stream>>>(
        inputs, hidden, wih, Wa, Wb, Wc, Wd, bih, out_hidden, out_wih);
}

// Round 2
// 167.757 us; speedup vs baseline: 1.3503x; 1.3503x over previous
//
#include <hip/hip_runtime.h>

// Problem constants: B=64, I=512, H=1024, D=I+H=1536
constexpr int Bn = 64;
constexpr int In = 512;
constexpr int Hn = 1024;
constexpr int Dn = 1536;
constexpr float ALPHA = 0.001f;
constexpr int ROWS_PER_WAVE = 8;

// Block = (k, half of b-range): 2048 blocks total.
//  - Stage Wa..Wd[k,:] into LDS once (24 KB) -> phase-2 reads come from LDS,
//    cutting per-row vmem instructions from 42 to 18 and deduping W traffic.
//  - Each wave owns 8 rows (b, k) and streams them with an explicit
//    double-buffered register prefetch: row r+1's wih/x loads are issued
//    before row r's reduce/update, so HBM loads stay continuously in flight.
__global__ __launch_bounds__(256) void prnn_fused_kernel(
    const float* __restrict__ inputs,   // B x I
    const float* __restrict__ hidden,   // B x H
    const float* __restrict__ wih,      // B x H x D
    const float* __restrict__ Wa,       // H x D
    const float* __restrict__ Wb,       // H x D
    const float* __restrict__ Wc,       // H x D
    const float* __restrict__ Wd,       // H x D
    const float* __restrict__ bih,      // H
    float* __restrict__ out_hidden,     // B x H
    float* __restrict__ out_wih)        // B x H x D
{
    __shared__ float4 sW[4 * (Dn / 4)];   // 4 tensors x 384 float4 = 24 KB

    const int k     = blockIdx.x >> 1;
    const int bbase = (blockIdx.x & 1) * 32;
    const int tid   = threadIdx.x;

    // Cooperative LDS stage of Wa..Wd row k (384 float4 per tensor).
    {
        const float4* wa4 = (const float4*)(Wa + (size_t)k * Dn);
        const float4* wb4 = (const float4*)(Wb + (size_t)k * Dn);
        const float4* wc4 = (const float4*)(Wc + (size_t)k * Dn);
        const float4* wd4 = (const float4*)(Wd + (size_t)k * Dn);
        #pragma unroll
        for (int e = 0; e < 2; ++e) {
            const int i = tid + e * 256;
            if (i < 384) {
                sW[i]        = wa4[i];
                sW[384 + i]  = wb4[i];
                sW[768 + i]  = wc4[i];
                sW[1152 + i] = wd4[i];
            }
        }
    }
    __syncthreads();

    const int wave = tid >> 6;
    const int lane = tid & 63;
    const int b0   = bbase + wave * ROWS_PER_WAVE;
    const float bk = bih[k];
    const int base = lane * 4;            // this lane's float offset in a 256-float chunk

    float4 wbufA[6], xbufA[6], wbufB[6], xbufB[6];

    auto load_row = [&](int b, float4 (&w)[6], float4 (&x)[6]) {
        const float* __restrict__ wrow = wih + ((size_t)b * Hn + k) * Dn;
        const float* __restrict__ xin  = inputs + b * In;
        const float* __restrict__ xhid = hidden + b * Hn;
        #pragma unroll
        for (int c = 0; c < 6; ++c) {
            const int idx = c * 256 + base;
            w[c] = *(const float4*)(wrow + idx);
            x[c] = (c < 2) ? *(const float4*)(xin + idx)
                           : *(const float4*)(xhid + (idx - In));
        }
    };

    load_row(b0, wbufA, xbufA);

    #pragma unroll
    for (int r = 0; r < ROWS_PER_WAVE; ++r) {
        const int b = b0 + r;
        float4 (&w)[6]  = (r & 1) ? wbufB : wbufA;
        float4 (&x)[6]  = (r & 1) ? xbufB : xbufA;
        float4 (&wn)[6] = (r & 1) ? wbufA : wbufB;
        float4 (&xn)[6] = (r & 1) ? xbufA : xbufB;

        // Prefetch next row's HBM loads before touching this row's data.
        if (r + 1 < ROWS_PER_WAVE) load_row(b + 1, wn, xn);

        // Dot product for this row.
        float acc = 0.0f;
        #pragma unroll
        for (int c = 0; c < 6; ++c)
            acc += w[c].x * x[c].x + w[c].y * x[c].y
                 + w[c].z * x[c].z + w[c].w * x[c].w;

        #pragma unroll
        for (int off = 32; off > 0; off >>= 1)
            acc += __shfl_xor(acc, off, 64);

        const float y = tanhf(acc + bk);
        if (lane == 0) out_hidden[b * Hn + k] = y;

        // Update phase: W from LDS, wih/x from registers, stream the store.
        float* __restrict__ orow = out_wih + ((size_t)b * Hn + k) * Dn;
        #pragma unroll
        for (int c = 0; c < 6; ++c) {
            const int e = c * 64 + lane;              // float4 index in a tensor row
            const float4 a4 = sW[e];
            const float4 b4 = sW[384 + e];
            const float4 c4 = sW[768 + e];
            const float4 d4 = sW[1152 + e];
            float4 o;
            o.x = w[c].x + ALPHA * (y * x[c].x * a4.x + x[c].x * b4.x + y * c4.x + d4.x);
            o.y = w[c].y + ALPHA * (y * x[c].y * a4.y + x[c].y * b4.y + y * c4.y + d4.y);
            o.z = w[c].z + ALPHA * (y * x[c].z * a4.z + x[c].z * b4.z + y * c4.z + d4.z);
            o.w = w[c].w + ALPHA * (y * x[c].w * a4.w + x[c].w * b4.w + y * c4.w + d4.w);
            *(float4*)(orow + c * 256 + base) = o;
        }
    }
}

extern "C" void kernel_launch(void* const* d_in, const int* in_sizes, int n_in,
                              void* d_out, int out_size, void* d_ws, size_t ws_size,
                              hipStream_t stream) {
    const float* inputs = (const float*)d_in[0];
    const float* hidden = (const float*)d_in[1];
    const float* wih    = (const float*)d_in[2];
    const float* Wa     = (const float*)d_in[3];
    const float* Wb     = (const float*)d_in[4];
    const float* Wc     = (const float*)d_in[5];
    const float* Wd     = (const float*)d_in[6];
    const float* bih    = (const float*)d_in[7];
    // d_in[8] = W_dop, d_in[9] = b_dop feed only _dopamine, which the
    // reference does not return -> dead code, skipped.

    float* out_hidden = (float*)d_out;                    // B*H floats
    float* out_wih    = (float*)d_out + (size_t)Bn * Hn;  // B*H*D floats

    // 2 blocks per k (32 b-values each) -> 2048 blocks of 256 threads.
    prnn_fused_kernel<<<dim3(Hn * 2), dim3(256), 0, stream>>>(
        inputs, hidden, wih, Wa, Wb, Wc, Wd, bih, out_hidden, out_wih);
}

// Round 4
// 161.035 us; speedup vs baseline: 1.4067x; 1.0417x over previous
//
#include <hip/hip_runtime.h>

// Problem constants: B=64, I=512, H=1024, D=I+H=1536
constexpr int Bn = 64;
constexpr int In = 512;
constexpr int Hn = 1024;
constexpr int Dn = 1536;
constexpr float ALPHA = 0.001f;
constexpr int RPW = 8;                 // rows per wave

// Native 4-float vector for __builtin_nontemporal_store (HIP float4 is a
// class type the builtin rejects; this alias is layout-identical).
typedef float nfloat4 __attribute__((ext_vector_type(4)));

// Block = (k, half of b-range): 2048 blocks.
//  - Wa..Wd[k,:] staged to LDS once (24 KB).
//  - Each wave owns 8 rows (b, k). Software pipeline:
//      wih prefetch 2 rows deep (HBM ~900 cyc), x prefetch 1 row deep (L2 ~200 cyc).
//  - out_wih written with nontemporal stores: write-once stream must not evict
//    the wih read stream from L2/L3 (L3 carries ~100 MB of wih across replays).
__global__ __launch_bounds__(256) void prnn_fused_kernel(
    const float* __restrict__ inputs,   // B x I
    const float* __restrict__ hidden,   // B x H
    const float* __restrict__ wih,      // B x H x D
    const float* __restrict__ Wa,       // H x D
    const float* __restrict__ Wb,       // H x D
    const float* __restrict__ Wc,       // H x D
    const float* __restrict__ Wd,       // H x D
    const float* __restrict__ bih,      // H
    float* __restrict__ out_hidden,     // B x H
    float* __restrict__ out_wih)        // B x H x D
{
    __shared__ float4 sW[4 * (Dn / 4)];   // 24 KB

    const int k     = blockIdx.x >> 1;
    const int bbase = (blockIdx.x & 1) * 32;
    const int tid   = threadIdx.x;

    // Cooperative LDS stage of Wa..Wd row k (384 float4 per tensor).
    {
        const float4* wa4 = (const float4*)(Wa + (size_t)k * Dn);
        const float4* wb4 = (const float4*)(Wb + (size_t)k * Dn);
        const float4* wc4 = (const float4*)(Wc + (size_t)k * Dn);
        const float4* wd4 = (const float4*)(Wd + (size_t)k * Dn);
        #pragma unroll
        for (int e = 0; e < 2; ++e) {
            const int i = tid + e * 256;
            if (i < 384) {
                sW[i]        = wa4[i];
                sW[384 + i]  = wb4[i];
                sW[768 + i]  = wc4[i];
                sW[1152 + i] = wd4[i];
            }
        }
    }
    __syncthreads();

    const int wave = tid >> 6;
    const int lane = tid & 63;
    const int b0   = bbase + wave * RPW;
    const float bk = bih[k];
    const int base = lane * 4;

    float4 wbuf[3][6];   // wih: 2-deep prefetch (3 rotating buffers)
    float4 xbuf[2][6];   // x:   1-deep prefetch

    auto load_w = [&](int r, float4 (&w)[6]) {
        const float* __restrict__ wrow = wih + ((size_t)(b0 + r) * Hn + k) * Dn;
        #pragma unroll
        for (int c = 0; c < 6; ++c)
            w[c] = *(const float4*)(wrow + c * 256 + base);
    };
    auto load_x = [&](int r, float4 (&x)[6]) {
        const int b = b0 + r;
        const float* __restrict__ xin  = inputs + b * In;
        const float* __restrict__ xhid = hidden + b * Hn;
        #pragma unroll
        for (int c = 0; c < 6; ++c) {
            const int idx = c * 256 + base;
            x[c] = (c < 2) ? *(const float4*)(xin + idx)
                           : *(const float4*)(xhid + (idx - In));
        }
    };

    // Prologue: fill the pipeline.
    load_w(0, wbuf[0]);
    load_w(1, wbuf[1]);
    load_x(0, xbuf[0]);

    #pragma unroll
    for (int r = 0; r < RPW; ++r) {     // fully unrolled: all buffer indices static
        // Issue next loads before consuming this row (keeps HBM queue full).
        if (r + 1 < RPW) load_x(r + 1, xbuf[(r + 1) & 1]);
        if (r + 2 < RPW) load_w(r + 2, wbuf[(r + 2) % 3]);

        float4 (&w)[6] = wbuf[r % 3];
        float4 (&x)[6] = xbuf[r & 1];

        float acc = 0.0f;
        #pragma unroll
        for (int c = 0; c < 6; ++c)
            acc += w[c].x * x[c].x + w[c].y * x[c].y
                 + w[c].z * x[c].z + w[c].w * x[c].w;

        #pragma unroll
        for (int off = 32; off > 0; off >>= 1)
            acc += __shfl_xor(acc, off, 64);

        const float y = tanhf(acc + bk);
        const int b = b0 + r;
        if (lane == 0) out_hidden[b * Hn + k] = y;

        float* __restrict__ orow = out_wih + ((size_t)b * Hn + k) * Dn;
        #pragma unroll
        for (int c = 0; c < 6; ++c) {
            const int e = c * 64 + lane;
            const float4 a4 = sW[e];
            const float4 b4 = sW[384 + e];
            const float4 c4 = sW[768 + e];
            const float4 d4 = sW[1152 + e];
            nfloat4 o;
            o.x = w[c].x + ALPHA * (y * x[c].x * a4.x + x[c].x * b4.x + y * c4.x + d4.x);
            o.y = w[c].y + ALPHA * (y * x[c].y * a4.y + x[c].y * b4.y + y * c4.y + d4.y);
            o.z = w[c].z + ALPHA * (y * x[c].z * a4.z + x[c].z * b4.z + y * c4.z + d4.z);
            o.w = w[c].w + ALPHA * (y * x[c].w * a4.w + x[c].w * b4.w + y * c4.w + d4.w);
            __builtin_nontemporal_store(o, (nfloat4*)(orow + c * 256 + base));
        }
    }
}

extern "C" void kernel_launch(void* const* d_in, const int* in_sizes, int n_in,
                              void* d_out, int out_size, void* d_ws, size_t ws_size,
                              hipStream_t stream) {
    const float* inputs = (const float*)d_in[0];
    const float* hidden = (const float*)d_in[1];
    const float* wih    = (const float*)d_in[2];
    const float* Wa     = (const float*)d_in[3];
    const float* Wb     = (const float*)d_in[4];
    const float* Wc     = (const float*)d_in[5];
    const float* Wd     = (const float*)d_in[6];
    const float* bih    = (const float*)d_in[7];
    // d_in[8] = W_dop, d_in[9] = b_dop feed only _dopamine (not returned) -> skipped.

    float* out_hidden = (float*)d_out;                    // B*H floats
    float* out_wih    = (float*)d_out + (size_t)Bn * Hn;  // B*H*D floats

    prnn_fused_kernel<<<dim3(Hn * 2), dim3(256), 0, stream>>>(
        inputs, hidden, wih, Wa, Wb, Wc, Wd, bih, out_hidden, out_wih);
}